// Round 8
// baseline (70.574 us; speedup 1.0000x reference)
//
#include <hip/hip_runtime.h>
#include <math.h>

namespace {

constexpr int N  = 4096;
constexpr int E  = 256;
constexpr int H  = 8;
constexpr int DH = 32;
constexpr int BS = 8;
// fold 1/sqrt(DH) and log2(e): softmax in exp2 domain, no max subtraction
// (f32-safe: |s*CL| realistic max ~16, overflow at 127 -> 27 sigma margin)
constexpr float CL = 0.17677669529663687f * 1.4426950408889634f;

typedef __bf16 bf16x8 __attribute__((ext_vector_type(8)));
typedef __bf16 bf16x4 __attribute__((ext_vector_type(4)));
typedef float  f32x4  __attribute__((ext_vector_type(4)));

#if __has_builtin(__builtin_amdgcn_exp2f)
#define EXP2F(x) __builtin_amdgcn_exp2f(x)
#else
#define EXP2F(x) __expf((x) * 0.6931471805599453f)
#endif

__device__ inline bf16x8 pack8(float4 a, float4 b) {
  bf16x8 r;
  r[0] = (__bf16)a.x; r[1] = (__bf16)a.y; r[2] = (__bf16)a.z; r[3] = (__bf16)a.w;
  r[4] = (__bf16)b.x; r[5] = (__bf16)b.y; r[6] = (__bf16)b.z; r[7] = (__bf16)b.w;
  return r;
}

// ---------------------------------------------------------------------------
// prep: one memory-bound pass producing all bf16 operands. (unchanged)
// ---------------------------------------------------------------------------
__global__ __launch_bounds__(256) void prep_kernel(
    const float* __restrict__ x, const float* __restrict__ pe,
    const int* __restrict__ xb,
    const float* __restrict__ Wq, const float* __restrict__ Wk,
    const float* __restrict__ Wv, const float* __restrict__ Wo,
    __bf16* __restrict__ xpe, __bf16* __restrict__ xv,
    __bf16* __restrict__ wb, int* __restrict__ seg)
{
  const int bid = blockIdx.x;
  if (bid < 512) {
    const size_t e0 = ((size_t)bid * 256 + threadIdx.x) * 8;
    float4 a0 = *(const float4*)(x + e0);
    float4 a1 = *(const float4*)(x + e0 + 4);
    const float4 p0 = *(const float4*)(pe + e0);
    const float4 p1 = *(const float4*)(pe + e0 + 4);
    *reinterpret_cast<bf16x8*>(xv + e0) = pack8(a0, a1);
    a0.x += p0.x; a0.y += p0.y; a0.z += p0.z; a0.w += p0.w;
    a1.x += p1.x; a1.y += p1.y; a1.z += p1.z; a1.w += p1.w;
    *reinterpret_cast<bf16x8*>(xpe + e0) = pack8(a0, a1);
  } else if (bid < 640) {
    const size_t e0 = ((size_t)(bid - 512) * 256 + threadIdx.x) * 8;
    const int mat = (int)(e0 >> 16);
    const size_t off = e0 & 65535;
    const float* __restrict__ W =
        (mat == 0) ? Wq : (mat == 1) ? Wk : (mat == 2) ? Wv : Wo;
    *reinterpret_cast<bf16x8*>(wb + e0) =
        pack8(*(const float4*)(W + off), *(const float4*)(W + off + 4));
  } else {
    if (threadIdx.x <= BS) {
      const int t = threadIdx.x;
      int lo = 0, hi = N;
      while (lo < hi) { int mid = (lo + hi) >> 1; if (xb[mid] < t) lo = mid + 1; else hi = mid; }
      seg[t] = lo;
    }
  }
}

// ---------------------------------------------------------------------------
// MFMA QKV, pure bf16 operands. (unchanged from round 7)
// ---------------------------------------------------------------------------
__global__ __launch_bounds__(256) void qkv_mfma(
    const __bf16* __restrict__ xpe, const __bf16* __restrict__ xv,
    const __bf16* __restrict__ wb,
    const float* __restrict__ bq, const float* __restrict__ bk,
    const float* __restrict__ bv,
    __bf16* __restrict__ qo, __bf16* __restrict__ ko,
    __bf16* __restrict__ vt)
{
  const int mat  = blockIdx.y;
  const int m0   = (blockIdx.x >> 1) * 16;
  const int half = blockIdx.x & 1;
  const int wv   = threadIdx.x >> 6;
  const int lane = threadIdx.x & 63;
  const int l15  = lane & 15, g = lane >> 4;
  const int cb0  = half * 128 + wv * 32;

  const __bf16* __restrict__ A = (mat < 2) ? xpe : xv;
  const __bf16* __restrict__ W = wb + (size_t)mat * E * E;
  const int mrow = m0 + l15;

  bf16x8 af[8];
#pragma unroll
  for (int kk = 0; kk < 8; ++kk)
    af[kk] = *reinterpret_cast<const bf16x8*>(A + (size_t)mrow * E + kk * 32 + 8 * g);

  f32x4 acc[2];
  acc[0] = f32x4{0.f, 0.f, 0.f, 0.f};
  acc[1] = f32x4{0.f, 0.f, 0.f, 0.f};

#pragma unroll
  for (int kk = 0; kk < 8; ++kk)
#pragma unroll
    for (int nt = 0; nt < 2; ++nt) {
      const bf16x8 wf = *reinterpret_cast<const bf16x8*>(
          W + (size_t)(cb0 + nt * 16 + l15) * E + kk * 32 + 8 * g);
      acc[nt] = __builtin_amdgcn_mfma_f32_16x16x32_bf16(wf, af[kk], acc[nt], 0, 0, 0);
    }

  if (mat < 2) {
    __bf16* __restrict__ outb = mat ? ko : qo;
    const float* __restrict__ bi = mat ? bk : bq;
#pragma unroll
    for (int nt = 0; nt < 2; ++nt) {
      const int n_base = cb0 + nt * 16 + 4 * g;
      const float4 bb = *(const float4*)(bi + n_base);
      bf16x4 o;
      o.x = (__bf16)(acc[nt][0] + bb.x);
      o.y = (__bf16)(acc[nt][1] + bb.y);
      o.z = (__bf16)(acc[nt][2] + bb.z);
      o.w = (__bf16)(acc[nt][3] + bb.w);
      *reinterpret_cast<bf16x4*>(outb + (size_t)mrow * E + n_base) = o;
    }
  } else {
#pragma unroll
    for (int nt = 0; nt < 2; ++nt) {
      const int n_base = cb0 + nt * 16 + 4 * g;
      const float4 bb = *(const float4*)(bv + n_base);
      const float bbr[4] = {bb.x, bb.y, bb.z, bb.w};
#pragma unroll
      for (int r = 0; r < 4; ++r)
        vt[(size_t)(n_base + r) * N + mrow] = (__bf16)(acc[nt][r] + bbr[r]);
    }
  }
}

// ---------------------------------------------------------------------------
// Fused attention + projection + residual + LayerNorm, KEY-SPLIT x2.
// Block = 16 query rows, 1024 threads = 16 waves: wave = (head h, split s).
// Fixed-base exp2 softmax makes key-partials associative: each (h,s) wave
// processes tiles t = s, s+2, ... of its segment, depositing UNNORMALIZED
// bf16 partial ctx (cl[s]) + partial row-sums (lsW[s]) in LDS. Phase B
// (16 waves x 16-col slices) combines halves, normalizes per (row l15,
// head kk) -- head == kk because DH=32 -- then proj + residual + LN.
// 16 waves/CU vs round-7's 8: halves the exposed-latency time.
// ---------------------------------------------------------------------------
__global__ __launch_bounds__(1024) void attn_proj_ln(
    const __bf16* __restrict__ qb, const __bf16* __restrict__ kb,
    const __bf16* __restrict__ vt, const int* __restrict__ xb,
    const int* __restrict__ seg,
    const float* __restrict__ x, const __bf16* __restrict__ wo,
    const float* __restrict__ bo, const float* __restrict__ gamma,
    const float* __restrict__ beta, float* __restrict__ out)
{
  const int m0   = blockIdx.x * 16;
  const int wv   = threadIdx.x >> 6;    // [0,16)
  const int h    = wv & 7;              // head
  const int s    = wv >> 3;             // key-split half
  const int lane = threadIdx.x & 63;
  const int l15  = lane & 15;
  const int g    = lane >> 4;
  const int hd   = h * DH;
  const int qrow = m0 + l15;

  __shared__ __bf16 cl[2][16][268];     // unnormalized partial ctx per split
  __shared__ float  lsW[2][8][16];      // partial row-sum per (split, head)
  __shared__ float  redS[16][16];
  __shared__ float  redQ[16][16];

  // ======== phase A: attention (this wave: head h, key tiles s, s+2, ...) ==
  {
    const int b  = xb[qrow];
    const int lo = seg[b];
    const int hi = seg[b + 1];

    const bf16x8 qf = *reinterpret_cast<const bf16x8*>(
        qb + (size_t)qrow * E + hd + g * 8);

    const int kstart = __shfl(lo, 0, 64);
    const int kend   = __shfl(hi, 15, 64);
    const int base   = kstart & ~63;
    const int ntiles = (kend - base + 63) >> 6;

    const int base_l = ((l15 & 12) << 1) + (l15 & 3);  // 8*(l15>>2) + (l15&3)

    f32x4 acc0 = {0.f, 0.f, 0.f, 0.f};
    f32x4 acc1 = {0.f, 0.f, 0.f, 0.f};
    float lsum = 0.f;

    for (int t = s; t < ntiles; t += 2) {
      const int j0 = base + (t << 6);
      bf16x8 kf[4];
#pragma unroll
      for (int mt = 0; mt < 4; ++mt) {
        const int krow = j0 + base_l + 32 * (mt >> 1) + 4 * (mt & 1);
        kf[mt] = *reinterpret_cast<const bf16x8*>(kb + (size_t)krow * E + hd + g * 8);
      }
      bf16x8 vf[2][2];
#pragma unroll
      for (int ks = 0; ks < 2; ++ks)
#pragma unroll
        for (int dh = 0; dh < 2; ++dh)
          vf[ks][dh] = *reinterpret_cast<const bf16x8*>(
              vt + (size_t)(hd + 16 * dh + l15) * N + j0 + 32 * ks + 8 * g);

      f32x4 sc4[4];
#pragma unroll
      for (int mt = 0; mt < 4; ++mt) {
        const f32x4 z = {0.f, 0.f, 0.f, 0.f};
        sc4[mt] = __builtin_amdgcn_mfma_f32_16x16x32_bf16(kf[mt], qf, z, 0, 0, 0);
      }

      bf16x8 pa[2];
#pragma unroll
      for (int ks = 0; ks < 2; ++ks)
#pragma unroll
        for (int b_ = 0; b_ < 2; ++b_)
#pragma unroll
          for (int r = 0; r < 4; ++r) {
            const int key = j0 + 32 * ks + 8 * g + 4 * b_ + r;
            const float sv = sc4[2 * ks + b_][r] * CL;
            const float e  = (key >= lo && key < hi) ? EXP2F(sv) : 0.f;
            lsum += e;
            pa[ks][4 * b_ + r] = (__bf16)e;
          }

#pragma unroll
      for (int ks = 0; ks < 2; ++ks) {
        acc0 = __builtin_amdgcn_mfma_f32_16x16x32_bf16(pa[ks], vf[ks][0], acc0, 0, 0, 0);
        acc1 = __builtin_amdgcn_mfma_f32_16x16x32_bf16(pa[ks], vf[ks][1], acc1, 0, 0, 0);
      }
    }

    // partial row-sum for rows l15 (this head, this split)
    lsum += __shfl_xor(lsum, 16, 64);
    lsum += __shfl_xor(lsum, 32, 64);
    if (lane < 16) lsW[s][h][lane] = lsum;

    // unnormalized partial ctx tile -> LDS (bf16)
#pragma unroll
    for (int r = 0; r < 4; ++r) {
      cl[s][4 * g + r][hd + l15]      = (__bf16)(acc0[r]);
      cl[s][4 * g + r][hd + 16 + l15] = (__bf16)(acc1[r]);
    }
  }
  __syncthreads();

  // ======== phase B: combine + normalize + proj + residual + LayerNorm ====
  {
    const int c0 = wv * 16;             // this wave's 16 output cols

    bf16x8 af[8];
#pragma unroll
    for (int kk = 0; kk < 8; ++kk) {
      const int cc = kk * 32 + 8 * g;
      const bf16x8 a0 = *reinterpret_cast<const bf16x8*>(&cl[0][l15][cc]);
      const bf16x8 a1 = *reinterpret_cast<const bf16x8*>(&cl[1][l15][cc]);
      const float inv = 1.0f / (lsW[0][kk][l15] + lsW[1][kk][l15]);
#pragma unroll
      for (int i = 0; i < 8; ++i)
        af[kk][i] = (__bf16)(((float)a0[i] + (float)a1[i]) * inv);
    }

    f32x4 acc = {0.f, 0.f, 0.f, 0.f};
#pragma unroll
    for (int kk = 0; kk < 8; ++kk) {
      const bf16x8 wf = *reinterpret_cast<const bf16x8*>(
          wo + (size_t)(c0 + l15) * E + kk * 32 + 8 * g);
      acc = __builtin_amdgcn_mfma_f32_16x16x32_bf16(af[kk], wf, acc, 0, 0, 0);
    }

    // y[m0+4g+r][c0+l15] = acc[r] + bo + x ; LN stats
    const int c = c0 + l15;
    const float bb = bo[c];
    float yv[4];
    float s1[4], s2[4];
#pragma unroll
    for (int r = 0; r < 4; ++r) {
      const int row = m0 + 4 * g + r;
      const float y = acc[r] + bb + x[(size_t)row * E + c];
      yv[r] = y;
      s1[r] = y;
      s2[r] = y * y;
    }
#pragma unroll
    for (int off = 1; off < 16; off <<= 1) {
#pragma unroll
      for (int r = 0; r < 4; ++r) {
        s1[r] += __shfl_xor(s1[r], off, 64);
        s2[r] += __shfl_xor(s2[r], off, 64);
      }
    }
    if (l15 == 0) {
#pragma unroll
      for (int r = 0; r < 4; ++r) {
        redS[wv][4 * g + r] = s1[r];
        redQ[wv][4 * g + r] = s2[r];
      }
    }
    __syncthreads();
    float mu[4], rs[4];
#pragma unroll
    for (int r = 0; r < 4; ++r) {
      float ts = 0.f, tq = 0.f;
#pragma unroll
      for (int w = 0; w < 16; ++w) {
        ts += redS[w][4 * g + r];
        tq += redQ[w][4 * g + r];
      }
      mu[r] = ts * (1.0f / E);
      const float var = tq * (1.0f / E) - mu[r] * mu[r];
      rs[r] = rsqrtf(var + 1e-5f);
    }
    const float gg = gamma[c];
    const float bt = beta[c];
#pragma unroll
    for (int r = 0; r < 4; ++r) {
      const int row = m0 + 4 * g + r;
      out[(size_t)row * E + c] = (yv[r] - mu[r]) * rs[r] * gg + bt;
    }
  }
}

}  // namespace

extern "C" void kernel_launch(void* const* d_in, const int* in_sizes, int n_in,
                              void* d_out, int out_size, void* d_ws, size_t ws_size,
                              hipStream_t stream) {
  const float* x     = (const float*)d_in[0];
  const float* pe    = (const float*)d_in[1];
  const int*   xb    = (const int*)d_in[2];
  const float* Wq    = (const float*)d_in[3];
  const float* Wk    = (const float*)d_in[4];
  const float* Wv    = (const float*)d_in[5];
  const float* bq    = (const float*)d_in[6];
  const float* bk    = (const float*)d_in[7];
  const float* bv    = (const float*)d_in[8];
  const float* Wo    = (const float*)d_in[9];
  const float* bo    = (const float*)d_in[10];
  const float* gamma = (const float*)d_in[11];
  const float* beta  = (const float*)d_in[12];
  float* out = (float*)d_out;

  char* wsb = (char*)d_ws;
  const size_t NE = (size_t)N * E;          // 1,048,576 elements
  __bf16* qb16  = (__bf16*)(wsb);                   // 2 MB
  __bf16* kb16  = (__bf16*)(wsb + 2 * NE);          // 2 MB (vt follows: safe tail overrun)
  __bf16* vt16  = (__bf16*)(wsb + 4 * NE);          // 2 MB  [E][N] (xpe follows)
  __bf16* xpe16 = (__bf16*)(wsb + 6 * NE);          // 2 MB
  __bf16* xv16  = (__bf16*)(wsb + 8 * NE);          // 2 MB
  __bf16* wb16  = (__bf16*)(wsb + 10 * NE);         // 512 KB (4 mats)
  int*    seg   = (int*)(wsb + 10 * NE + 4 * (size_t)E * E * 2);

  prep_kernel<<<dim3(641), 256, 0, stream>>>(x, pe, xb, Wq, Wk, Wv, Wo,
                                             xpe16, xv16, wb16, seg);
  qkv_mfma<<<dim3(512, 3), 256, 0, stream>>>(xpe16, xv16, wb16, bq, bk, bv,
                                             qb16, kb16, vt16);
  attn_proj_ln<<<dim3(256), 1024, 0, stream>>>(qb16, kb16, vt16, xb, seg,
                                               x, wb16 + 3 * (size_t)E * E,
                                               bo, gamma, beta, out);
}

// Round 9
// 69.769 us; speedup vs baseline: 1.0115x; 1.0115x over previous
//
#include <hip/hip_runtime.h>
#include <math.h>

namespace {

constexpr int N  = 4096;
constexpr int E  = 256;
constexpr int H  = 8;
constexpr int DH = 32;
constexpr int BS = 8;
// fold 1/sqrt(DH) and log2(e): softmax in exp2 domain, no max subtraction
// (f32-safe: |s*CL| realistic max ~16, overflow at 127 -> 27 sigma margin)
constexpr float CL = 0.17677669529663687f * 1.4426950408889634f;

typedef __bf16 bf16x8 __attribute__((ext_vector_type(8)));
typedef __bf16 bf16x4 __attribute__((ext_vector_type(4)));
typedef float  f32x4  __attribute__((ext_vector_type(4)));

#if __has_builtin(__builtin_amdgcn_exp2f)
#define EXP2F(x) __builtin_amdgcn_exp2f(x)
#else
#define EXP2F(x) __expf((x) * 0.6931471805599453f)
#endif

__device__ inline bf16x8 pack8(float4 a, float4 b) {
  bf16x8 r;
  r[0] = (__bf16)a.x; r[1] = (__bf16)a.y; r[2] = (__bf16)a.z; r[3] = (__bf16)a.w;
  r[4] = (__bf16)b.x; r[5] = (__bf16)b.y; r[6] = (__bf16)b.z; r[7] = (__bf16)b.w;
  return r;
}

// ---------------------------------------------------------------------------
// prep: one memory-bound pass producing all bf16 operands. (unchanged)
// ---------------------------------------------------------------------------
__global__ __launch_bounds__(256) void prep_kernel(
    const float* __restrict__ x, const float* __restrict__ pe,
    const int* __restrict__ xb,
    const float* __restrict__ Wq, const float* __restrict__ Wk,
    const float* __restrict__ Wv, const float* __restrict__ Wo,
    __bf16* __restrict__ xpe, __bf16* __restrict__ xv,
    __bf16* __restrict__ wb, int* __restrict__ seg)
{
  const int bid = blockIdx.x;
  if (bid < 512) {
    const size_t e0 = ((size_t)bid * 256 + threadIdx.x) * 8;
    float4 a0 = *(const float4*)(x + e0);
    float4 a1 = *(const float4*)(x + e0 + 4);
    const float4 p0 = *(const float4*)(pe + e0);
    const float4 p1 = *(const float4*)(pe + e0 + 4);
    *reinterpret_cast<bf16x8*>(xv + e0) = pack8(a0, a1);
    a0.x += p0.x; a0.y += p0.y; a0.z += p0.z; a0.w += p0.w;
    a1.x += p1.x; a1.y += p1.y; a1.z += p1.z; a1.w += p1.w;
    *reinterpret_cast<bf16x8*>(xpe + e0) = pack8(a0, a1);
  } else if (bid < 640) {
    const size_t e0 = ((size_t)(bid - 512) * 256 + threadIdx.x) * 8;
    const int mat = (int)(e0 >> 16);
    const size_t off = e0 & 65535;
    const float* __restrict__ W =
        (mat == 0) ? Wq : (mat == 1) ? Wk : (mat == 2) ? Wv : Wo;
    *reinterpret_cast<bf16x8*>(wb + e0) =
        pack8(*(const float4*)(W + off), *(const float4*)(W + off + 4));
  } else {
    if (threadIdx.x <= BS) {
      const int t = threadIdx.x;
      int lo = 0, hi = N;
      while (lo < hi) { int mid = (lo + hi) >> 1; if (xb[mid] < t) lo = mid + 1; else hi = mid; }
      seg[t] = lo;
    }
  }
}

// ---------------------------------------------------------------------------
// MFMA QKV with explicit W double-buffer: out = A @ W^T + b.
// Block = 16 rows x 128 cols, 4 waves (32-col slices), grid (512,3).
// kk-loop pipelined: wf for step kk+1 issued before the MFMAs of step kk
// consume the current pair (static names, fully unrolled -> no copies).
// launch_bounds(...,2) leaves the allocator 256-VGPR headroom so the
// hoisted af[8] + in-flight wf pair actually stay resident.
// ---------------------------------------------------------------------------
__global__ __launch_bounds__(256, 2) void qkv_mfma(
    const __bf16* __restrict__ xpe, const __bf16* __restrict__ xv,
    const __bf16* __restrict__ wb,
    const float* __restrict__ bq, const float* __restrict__ bk,
    const float* __restrict__ bv,
    __bf16* __restrict__ qo, __bf16* __restrict__ ko,
    __bf16* __restrict__ vt)
{
  const int mat  = blockIdx.y;
  const int m0   = (blockIdx.x >> 1) * 16;
  const int half = blockIdx.x & 1;
  const int wv   = threadIdx.x >> 6;
  const int lane = threadIdx.x & 63;
  const int l15  = lane & 15, g = lane >> 4;
  const int cb0  = half * 128 + wv * 32;

  const __bf16* __restrict__ A = (mat < 2) ? xpe : xv;
  const __bf16* __restrict__ W = wb + (size_t)mat * E * E;
  const int mrow = m0 + l15;

  const __bf16* __restrict__ w0p = W + (size_t)(cb0 + l15) * E + 8 * g;
  const __bf16* __restrict__ w1p = W + (size_t)(cb0 + 16 + l15) * E + 8 * g;

  bf16x8 af[8];
#pragma unroll
  for (int kk = 0; kk < 8; ++kk)
    af[kk] = *reinterpret_cast<const bf16x8*>(A + (size_t)mrow * E + kk * 32 + 8 * g);

  f32x4 acc0 = {0.f, 0.f, 0.f, 0.f};
  f32x4 acc1 = {0.f, 0.f, 0.f, 0.f};

  bf16x8 wA0 = *reinterpret_cast<const bf16x8*>(w0p);
  bf16x8 wA1 = *reinterpret_cast<const bf16x8*>(w1p);

#pragma unroll
  for (int kk = 0; kk < 8; ++kk) {
    bf16x8 wB0, wB1;
    if (kk < 7) {
      wB0 = *reinterpret_cast<const bf16x8*>(w0p + (kk + 1) * 32);
      wB1 = *reinterpret_cast<const bf16x8*>(w1p + (kk + 1) * 32);
    }
    acc0 = __builtin_amdgcn_mfma_f32_16x16x32_bf16(wA0, af[kk], acc0, 0, 0, 0);
    acc1 = __builtin_amdgcn_mfma_f32_16x16x32_bf16(wA1, af[kk], acc1, 0, 0, 0);
    if (kk < 7) { wA0 = wB0; wA1 = wB1; }
  }

  if (mat < 2) {
    __bf16* __restrict__ outb = mat ? ko : qo;
    const float* __restrict__ bi = mat ? bk : bq;
    f32x4 accs[2] = {acc0, acc1};
#pragma unroll
    for (int nt = 0; nt < 2; ++nt) {
      const int n_base = cb0 + nt * 16 + 4 * g;
      const float4 bb = *(const float4*)(bi + n_base);
      bf16x4 o;
      o.x = (__bf16)(accs[nt][0] + bb.x);
      o.y = (__bf16)(accs[nt][1] + bb.y);
      o.z = (__bf16)(accs[nt][2] + bb.z);
      o.w = (__bf16)(accs[nt][3] + bb.w);
      *reinterpret_cast<bf16x4*>(outb + (size_t)mrow * E + n_base) = o;
    }
  } else {
    f32x4 accs[2] = {acc0, acc1};
#pragma unroll
    for (int nt = 0; nt < 2; ++nt) {
      const int n_base = cb0 + nt * 16 + 4 * g;
      const float4 bb = *(const float4*)(bv + n_base);
      const float bbr[4] = {bb.x, bb.y, bb.z, bb.w};
#pragma unroll
      for (int r = 0; r < 4; ++r)
        vt[(size_t)(n_base + r) * N + mrow] = (__bf16)(accs[nt][r] + bbr[r]);
    }
  }
}

// ---------------------------------------------------------------------------
// Fused attention + projection + residual + LayerNorm, SOFTWARE-PIPELINED.
// Block = 16 query rows, 512 threads = 8 waves, wave = head (round-7 shape).
// The key-tile loop is a 2-stage pipeline with STATIC buffer sets A/B:
// tile t+1's 8 global loads are issued before tile t's MFMA/exp2 block
// consumes the resident set, so ~8 loads stay in flight under compute
// (the round-4..8 kernels had ~2: compiler sank the loads -> serial L2
// latency chains; VGPR_Count 32 was the tell).
// ---------------------------------------------------------------------------
#define LOADK(KF, J0)                                                          \
  {                                                                            \
    const int jj = (J0);                                                       \
    KF##0 = *reinterpret_cast<const bf16x8*>(kb + (size_t)(jj + base_l) * E + hd + g * 8);          \
    KF##1 = *reinterpret_cast<const bf16x8*>(kb + (size_t)(jj + base_l + 4) * E + hd + g * 8);      \
    KF##2 = *reinterpret_cast<const bf16x8*>(kb + (size_t)(jj + base_l + 32) * E + hd + g * 8);     \
    KF##3 = *reinterpret_cast<const bf16x8*>(kb + (size_t)(jj + base_l + 36) * E + hd + g * 8);     \
  }
#define LOADV(VF, J0)                                                          \
  {                                                                            \
    const int jj = (J0);                                                       \
    VF##0 = *reinterpret_cast<const bf16x8*>(vt + (size_t)(hd + l15) * N + jj + 8 * g);             \
    VF##1 = *reinterpret_cast<const bf16x8*>(vt + (size_t)(hd + 16 + l15) * N + jj + 8 * g);        \
    VF##2 = *reinterpret_cast<const bf16x8*>(vt + (size_t)(hd + l15) * N + jj + 32 + 8 * g);        \
    VF##3 = *reinterpret_cast<const bf16x8*>(vt + (size_t)(hd + 16 + l15) * N + jj + 32 + 8 * g);   \
  }
// COMPUTE consumes kf set (QK), builds pa, applies PV with vf set.
#define COMPUTE(KF, VF, J0)                                                    \
  {                                                                            \
    const int j0c = (J0);                                                      \
    const f32x4 z = {0.f, 0.f, 0.f, 0.f};                                      \
    f32x4 s0 = __builtin_amdgcn_mfma_f32_16x16x32_bf16(KF##0, qf, z, 0, 0, 0); \
    f32x4 s1 = __builtin_amdgcn_mfma_f32_16x16x32_bf16(KF##1, qf, z, 0, 0, 0); \
    f32x4 s2 = __builtin_amdgcn_mfma_f32_16x16x32_bf16(KF##2, qf, z, 0, 0, 0); \
    f32x4 s3 = __builtin_amdgcn_mfma_f32_16x16x32_bf16(KF##3, qf, z, 0, 0, 0); \
    bf16x8 pa0, pa1;                                                           \
    _Pragma("unroll")                                                          \
    for (int b_ = 0; b_ < 2; ++b_)                                             \
      _Pragma("unroll")                                                        \
      for (int r = 0; r < 4; ++r) {                                            \
        const int key0 = j0c + 8 * g + 4 * b_ + r;                             \
        const float v0 = (b_ ? s1[r] : s0[r]) * CL;                            \
        const float e0 = (key0 >= lo && key0 < hi) ? EXP2F(v0) : 0.f;          \
        lsum += e0;                                                            \
        pa0[4 * b_ + r] = (__bf16)e0;                                          \
        const int key1 = key0 + 32;                                            \
        const float v1 = (b_ ? s3[r] : s2[r]) * CL;                            \
        const float e1 = (key1 >= lo && key1 < hi) ? EXP2F(v1) : 0.f;          \
        lsum += e1;                                                            \
        pa1[4 * b_ + r] = (__bf16)e1;                                          \
      }                                                                        \
    acc0 = __builtin_amdgcn_mfma_f32_16x16x32_bf16(pa0, VF##0, acc0, 0, 0, 0); \
    acc1 = __builtin_amdgcn_mfma_f32_16x16x32_bf16(pa0, VF##1, acc1, 0, 0, 0); \
    acc0 = __builtin_amdgcn_mfma_f32_16x16x32_bf16(pa1, VF##2, acc0, 0, 0, 0); \
    acc1 = __builtin_amdgcn_mfma_f32_16x16x32_bf16(pa1, VF##3, acc1, 0, 0, 0); \
  }

__global__ __launch_bounds__(512, 2) void attn_proj_ln(
    const __bf16* __restrict__ qb, const __bf16* __restrict__ kb,
    const __bf16* __restrict__ vt, const int* __restrict__ xb,
    const int* __restrict__ seg,
    const float* __restrict__ x, const __bf16* __restrict__ wo,
    const float* __restrict__ bo, const float* __restrict__ gamma,
    const float* __restrict__ beta, float* __restrict__ out)
{
  const int m0   = blockIdx.x * 16;
  const int h    = threadIdx.x >> 6;    // wave = head
  const int lane = threadIdx.x & 63;
  const int l15  = lane & 15;
  const int g    = lane >> 4;
  const int hd   = h * DH;
  const int qrow = m0 + l15;

  __shared__ __bf16 cl[16][264];        // ctx tile, padded stride
  __shared__ float redS[8][16];
  __shared__ float redQ[8][16];

  // ======== phase A: attention (2-stage pipelined) ========
  {
    const int b  = xb[qrow];
    const int lo = seg[b];
    const int hi = seg[b + 1];

    const bf16x8 qf = *reinterpret_cast<const bf16x8*>(
        qb + (size_t)qrow * E + hd + g * 8);

    const int kstart = __shfl(lo, 0, 64);
    const int kend   = __shfl(hi, 15, 64);
    const int base   = kstart & ~63;

    const int base_l = ((l15 & 12) << 1) + (l15 & 3);  // 8*(l15>>2) + (l15&3)

    f32x4 acc0 = {0.f, 0.f, 0.f, 0.f};
    f32x4 acc1 = {0.f, 0.f, 0.f, 0.f};
    float lsum = 0.f;

    bf16x8 kA0, kA1, kA2, kA3, vA0, vA1, vA2, vA3;
    bf16x8 kB0, kB1, kB2, kB3, vB0, vB1, vB2, vB3;

    LOADK(kA, base)
    LOADV(vA, base)
    for (int j0 = base; j0 < kend; j0 += 128) {
      const bool hasB = (j0 + 64 < kend);
      if (hasB) { LOADK(kB, j0 + 64) LOADV(vB, j0 + 64) }
      COMPUTE(kA, vA, j0)
      if (hasB) {
        if (j0 + 128 < kend) { LOADK(kA, j0 + 128) LOADV(vA, j0 + 128) }
        COMPUTE(kB, vB, j0 + 64)
      }
    }

    lsum += __shfl_xor(lsum, 16, 64);
    lsum += __shfl_xor(lsum, 32, 64);
    const float inv = 1.0f / lsum;
    float invr[4];
#pragma unroll
    for (int r = 0; r < 4; ++r) invr[r] = __shfl(inv, 4 * g + r, 64);

#pragma unroll
    for (int r = 0; r < 4; ++r) {
      cl[4 * g + r][hd + l15]      = (__bf16)(acc0[r] * invr[r]);
      cl[4 * g + r][hd + 16 + l15] = (__bf16)(acc1[r] * invr[r]);
    }
  }
  __syncthreads();

  // ======== phase B: projection + residual + LayerNorm ========
  {
    bf16x8 af[8];
#pragma unroll
    for (int kk = 0; kk < 8; ++kk)
      af[kk] = *reinterpret_cast<const bf16x8*>(&cl[l15][kk * 32 + 8 * g]);

    f32x4 acc[2];
    acc[0] = f32x4{0.f, 0.f, 0.f, 0.f};
    acc[1] = f32x4{0.f, 0.f, 0.f, 0.f};

#pragma unroll
    for (int kk = 0; kk < 8; ++kk)
#pragma unroll
      for (int nt = 0; nt < 2; ++nt) {
        const bf16x8 wf = *reinterpret_cast<const bf16x8*>(
            wo + (size_t)(h * 32 + nt * 16 + l15) * E + kk * 32 + 8 * g);
        acc[nt] = __builtin_amdgcn_mfma_f32_16x16x32_bf16(af[kk], wf, acc[nt], 0, 0, 0);
      }

    float yv[2][4];
    float s1[4], s2[4];
#pragma unroll
    for (int r = 0; r < 4; ++r) { s1[r] = 0.f; s2[r] = 0.f; }
#pragma unroll
    for (int nt = 0; nt < 2; ++nt) {
      const int c = h * 32 + nt * 16 + l15;
      const float bb = bo[c];
#pragma unroll
      for (int r = 0; r < 4; ++r) {
        const int row = m0 + 4 * g + r;
        const float y = acc[nt][r] + bb + x[(size_t)row * E + c];
        yv[nt][r] = y;
        s1[r] += y;
        s2[r] += y * y;
      }
    }
#pragma unroll
    for (int off = 1; off < 16; off <<= 1) {
#pragma unroll
      for (int r = 0; r < 4; ++r) {
        s1[r] += __shfl_xor(s1[r], off, 64);
        s2[r] += __shfl_xor(s2[r], off, 64);
      }
    }
    if (l15 == 0) {
#pragma unroll
      for (int r = 0; r < 4; ++r) {
        redS[h][4 * g + r] = s1[r];
        redQ[h][4 * g + r] = s2[r];
      }
    }
    __syncthreads();
    float mu[4], rs[4];
#pragma unroll
    for (int r = 0; r < 4; ++r) {
      float ts = 0.f, tq = 0.f;
#pragma unroll
      for (int w = 0; w < 8; ++w) { ts += redS[w][4 * g + r]; tq += redQ[w][4 * g + r]; }
      mu[r] = ts * (1.0f / E);
      const float var = tq * (1.0f / E) - mu[r] * mu[r];
      rs[r] = rsqrtf(var + 1e-5f);
    }
#pragma unroll
    for (int nt = 0; nt < 2; ++nt) {
      const int c = h * 32 + nt * 16 + l15;
      const float gg = gamma[c];
      const float bt = beta[c];
#pragma unroll
      for (int r = 0; r < 4; ++r) {
        const int row = m0 + 4 * g + r;
        out[(size_t)row * E + c] = (yv[nt][r] - mu[r]) * rs[r] * gg + bt;
      }
    }
  }
}

}  // namespace

extern "C" void kernel_launch(void* const* d_in, const int* in_sizes, int n_in,
                              void* d_out, int out_size, void* d_ws, size_t ws_size,
                              hipStream_t stream) {
  const float* x     = (const float*)d_in[0];
  const float* pe    = (const float*)d_in[1];
  const int*   xb    = (const int*)d_in[2];
  const float* Wq    = (const float*)d_in[3];
  const float* Wk    = (const float*)d_in[4];
  const float* Wv    = (const float*)d_in[5];
  const float* bq    = (const float*)d_in[6];
  const float* bk    = (const float*)d_in[7];
  const float* bv    = (const float*)d_in[8];
  const float* Wo    = (const float*)d_in[9];
  const float* bo    = (const float*)d_in[10];
  const float* gamma = (const float*)d_in[11];
  const float* beta  = (const float*)d_in[12];
  float* out = (float*)d_out;

  char* wsb = (char*)d_ws;
  const size_t NE = (size_t)N * E;          // 1,048,576 elements
  __bf16* qb16  = (__bf16*)(wsb);                   // 2 MB
  __bf16* kb16  = (__bf16*)(wsb + 2 * NE);          // 2 MB
  __bf16* vt16  = (__bf16*)(wsb + 4 * NE);          // 2 MB  [E][N]
  __bf16* xpe16 = (__bf16*)(wsb + 6 * NE);          // 2 MB
  __bf16* xv16  = (__bf16*)(wsb + 8 * NE);          // 2 MB
  __bf16* wb16  = (__bf16*)(wsb + 10 * NE);         // 512 KB (4 mats)
  int*    seg   = (int*)(wsb + 10 * NE + 4 * (size_t)E * E * 2);

  prep_kernel<<<dim3(641), 256, 0, stream>>>(x, pe, xb, Wq, Wk, Wv, Wo,
                                             xpe16, xv16, wb16, seg);
  qkv_mfma<<<dim3(512, 3), 256, 0, stream>>>(xpe16, xv16, wb16, bq, bk, bv,
                                             qb16, kb16, vt16);
  attn_proj_ln<<<dim3(256), 512, 0, stream>>>(qb16, kb16, vt16, xb, seg,
                                              x, wb16 + 3 * (size_t)E * E,
                                              bo, gamma, beta, out);
}

// Round 10
// 61.679 us; speedup vs baseline: 1.1442x; 1.1312x over previous
//
#include <hip/hip_runtime.h>
#include <math.h>

namespace {

constexpr int N  = 4096;
constexpr int E  = 256;
constexpr int H  = 8;
constexpr int DH = 32;
constexpr int BS = 8;
// fold 1/sqrt(DH) and log2(e): softmax in exp2 domain, no max subtraction
// (f32-safe: |s*CL| realistic max ~16, overflow at 127 -> 27 sigma margin)
constexpr float CL = 0.17677669529663687f * 1.4426950408889634f;

typedef __bf16 bf16x8 __attribute__((ext_vector_type(8)));
typedef __bf16 bf16x4 __attribute__((ext_vector_type(4)));
typedef float  f32x4  __attribute__((ext_vector_type(4)));

#if __has_builtin(__builtin_amdgcn_exp2f)
#define EXP2F(x) __builtin_amdgcn_exp2f(x)
#else
#define EXP2F(x) __expf((x) * 0.6931471805599453f)
#endif

// async global->LDS DMA, 16B per lane; LDS dest is wave-uniform base + lane*16
#define GLOAD16(G, L)                                              \
  __builtin_amdgcn_global_load_lds(                                \
      (const __attribute__((address_space(1))) void*)(G),          \
      (__attribute__((address_space(3))) void*)(L), 16, 0, 0)

__device__ inline bf16x8 pack8(float4 a, float4 b) {
  bf16x8 r;
  r[0] = (__bf16)a.x; r[1] = (__bf16)a.y; r[2] = (__bf16)a.z; r[3] = (__bf16)a.w;
  r[4] = (__bf16)b.x; r[5] = (__bf16)b.y; r[6] = (__bf16)b.z; r[7] = (__bf16)b.w;
  return r;
}

// ---------------------------------------------------------------------------
// prep: one memory-bound pass producing all bf16 operands. (unchanged)
// ---------------------------------------------------------------------------
__global__ __launch_bounds__(256) void prep_kernel(
    const float* __restrict__ x, const float* __restrict__ pe,
    const int* __restrict__ xb,
    const float* __restrict__ Wq, const float* __restrict__ Wk,
    const float* __restrict__ Wv, const float* __restrict__ Wo,
    __bf16* __restrict__ xpe, __bf16* __restrict__ xv,
    __bf16* __restrict__ wb, int* __restrict__ seg)
{
  const int bid = blockIdx.x;
  if (bid < 512) {
    const size_t e0 = ((size_t)bid * 256 + threadIdx.x) * 8;
    float4 a0 = *(const float4*)(x + e0);
    float4 a1 = *(const float4*)(x + e0 + 4);
    const float4 p0 = *(const float4*)(pe + e0);
    const float4 p1 = *(const float4*)(pe + e0 + 4);
    *reinterpret_cast<bf16x8*>(xv + e0) = pack8(a0, a1);
    a0.x += p0.x; a0.y += p0.y; a0.z += p0.z; a0.w += p0.w;
    a1.x += p1.x; a1.y += p1.y; a1.z += p1.z; a1.w += p1.w;
    *reinterpret_cast<bf16x8*>(xpe + e0) = pack8(a0, a1);
  } else if (bid < 640) {
    const size_t e0 = ((size_t)(bid - 512) * 256 + threadIdx.x) * 8;
    const int mat = (int)(e0 >> 16);
    const size_t off = e0 & 65535;
    const float* __restrict__ W =
        (mat == 0) ? Wq : (mat == 1) ? Wk : (mat == 2) ? Wv : Wo;
    *reinterpret_cast<bf16x8*>(wb + e0) =
        pack8(*(const float4*)(W + off), *(const float4*)(W + off + 4));
  } else {
    if (threadIdx.x <= BS) {
      const int t = threadIdx.x;
      int lo = 0, hi = N;
      while (lo < hi) { int mid = (lo + hi) >> 1; if (xb[mid] < t) lo = mid + 1; else hi = mid; }
      seg[t] = lo;
    }
  }
}

// ---------------------------------------------------------------------------
// MFMA QKV with explicit W double-buffer. (unchanged from round 9)
// ---------------------------------------------------------------------------
__global__ __launch_bounds__(256, 2) void qkv_mfma(
    const __bf16* __restrict__ xpe, const __bf16* __restrict__ xv,
    const __bf16* __restrict__ wb,
    const float* __restrict__ bq, const float* __restrict__ bk,
    const float* __restrict__ bv,
    __bf16* __restrict__ qo, __bf16* __restrict__ ko,
    __bf16* __restrict__ vt)
{
  const int mat  = blockIdx.y;
  const int m0   = (blockIdx.x >> 1) * 16;
  const int half = blockIdx.x & 1;
  const int wv   = threadIdx.x >> 6;
  const int lane = threadIdx.x & 63;
  const int l15  = lane & 15, g = lane >> 4;
  const int cb0  = half * 128 + wv * 32;

  const __bf16* __restrict__ A = (mat < 2) ? xpe : xv;
  const __bf16* __restrict__ W = wb + (size_t)mat * E * E;
  const int mrow = m0 + l15;

  const __bf16* __restrict__ w0p = W + (size_t)(cb0 + l15) * E + 8 * g;
  const __bf16* __restrict__ w1p = W + (size_t)(cb0 + 16 + l15) * E + 8 * g;

  bf16x8 af[8];
#pragma unroll
  for (int kk = 0; kk < 8; ++kk)
    af[kk] = *reinterpret_cast<const bf16x8*>(A + (size_t)mrow * E + kk * 32 + 8 * g);

  f32x4 acc0 = {0.f, 0.f, 0.f, 0.f};
  f32x4 acc1 = {0.f, 0.f, 0.f, 0.f};

  bf16x8 wA0 = *reinterpret_cast<const bf16x8*>(w0p);
  bf16x8 wA1 = *reinterpret_cast<const bf16x8*>(w1p);

#pragma unroll
  for (int kk = 0; kk < 8; ++kk) {
    bf16x8 wB0, wB1;
    if (kk < 7) {
      wB0 = *reinterpret_cast<const bf16x8*>(w0p + (kk + 1) * 32);
      wB1 = *reinterpret_cast<const bf16x8*>(w1p + (kk + 1) * 32);
    }
    acc0 = __builtin_amdgcn_mfma_f32_16x16x32_bf16(wA0, af[kk], acc0, 0, 0, 0);
    acc1 = __builtin_amdgcn_mfma_f32_16x16x32_bf16(wA1, af[kk], acc1, 0, 0, 0);
    if (kk < 7) { wA0 = wB0; wA1 = wB1; }
  }

  if (mat < 2) {
    __bf16* __restrict__ outb = mat ? ko : qo;
    const float* __restrict__ bi = mat ? bk : bq;
    f32x4 accs[2] = {acc0, acc1};
#pragma unroll
    for (int nt = 0; nt < 2; ++nt) {
      const int n_base = cb0 + nt * 16 + 4 * g;
      const float4 bb = *(const float4*)(bi + n_base);
      bf16x4 o;
      o.x = (__bf16)(accs[nt][0] + bb.x);
      o.y = (__bf16)(accs[nt][1] + bb.y);
      o.z = (__bf16)(accs[nt][2] + bb.z);
      o.w = (__bf16)(accs[nt][3] + bb.w);
      *reinterpret_cast<bf16x4*>(outb + (size_t)mrow * E + n_base) = o;
    }
  } else {
    f32x4 accs[2] = {acc0, acc1};
#pragma unroll
    for (int nt = 0; nt < 2; ++nt) {
      const int n_base = cb0 + nt * 16 + 4 * g;
      const float4 bb = *(const float4*)(bv + n_base);
      const float bbr[4] = {bb.x, bb.y, bb.z, bb.w};
#pragma unroll
      for (int r = 0; r < 4; ++r)
        vt[(size_t)(n_base + r) * N + mrow] = (__bf16)(accs[nt][r] + bbr[r]);
    }
  }
}

// ---------------------------------------------------------------------------
// Fused attention + projection + residual + LayerNorm — LDS-STAGED K/V.
// Block = 16 query rows, 512 threads = 8 waves, wave = head.
// Per 64-key tile the block DMAs K[64][256] (32KB) + Vt[256][64] (32KB)
// into double-buffered LDS via global_load_lds (contiguous 1KB per wave
// instruction -> ~8x fewer VMEM transactions than the old per-fragment
// 16-row gathers, which were the txn-rate bottleneck: TLP and ILP changes
// were both null). XOR chunk-swizzle (16B units, cc ^= row&7) applied on
// the GLOBAL SOURCE at stage time (LDS dest of gload_lds must be linear)
// and on the LDS index at read time: K ds_reads 4-way conflicts, V 2-way.
// Pipeline: counted s_waitcnt vmcnt(8) (prefetch never drained mid-loop),
// raw s_barrier pairs, sched_barrier(0) fences.
// ---------------------------------------------------------------------------
#define STAGE(KD, VD, J0)                                                      \
  {                                                                            \
    const int jj = (J0);                                                       \
    _Pragma("unroll")                                                          \
    for (int i_ = 0; i_ < 4; ++i_) {                                           \
      const int rr = 8 * h + 2 * i_ + (lane >> 5);                             \
      const int cc = lane & 31;                                                \
      const __bf16* gsrc = kb + (size_t)(jj + rr) * E + ((cc ^ (rr & 7)) * 8); \
      GLOAD16(gsrc, (KD) + (8 * h + 2 * i_) * 256);                            \
    }                                                                          \
    _Pragma("unroll")                                                          \
    for (int i_ = 0; i_ < 4; ++i_) {                                           \
      const int dd = 32 * h + 8 * i_ + (lane >> 3);                            \
      const int cc = lane & 7;                                                 \
      const __bf16* gsrc = vt + (size_t)dd * N + jj + ((cc ^ (dd & 7)) * 8);   \
      GLOAD16(gsrc, (VD) + (32 * h + 8 * i_) * 64);                            \
    }                                                                          \
  }

__global__ __launch_bounds__(512) void attn_proj_ln(
    const __bf16* __restrict__ qb, const __bf16* __restrict__ kb,
    const __bf16* __restrict__ vt, const int* __restrict__ xb,
    const int* __restrict__ seg,
    const float* __restrict__ x, const __bf16* __restrict__ wo,
    const float* __restrict__ bo, const float* __restrict__ gamma,
    const float* __restrict__ beta, float* __restrict__ out)
{
  const int m0   = blockIdx.x * 16;
  const int h    = threadIdx.x >> 6;    // wave = head
  const int lane = threadIdx.x & 63;
  const int l15  = lane & 15;
  const int g    = lane >> 4;
  const int hd   = h * DH;
  const int qrow = m0 + l15;

  __shared__ __bf16 ldsK0[64 * 256];    // 32KB  K tile [key][dim], swizzled
  __shared__ __bf16 ldsK1[64 * 256];
  __shared__ __bf16 ldsV0[256 * 64];    // 32KB  Vt tile [dim][key], swizzled
  __shared__ __bf16 ldsV1[256 * 64];
  __shared__ __bf16 cl[16][264];        // ctx tile, padded stride
  __shared__ float redS[8][16];
  __shared__ float redQ[8][16];

  // ======== phase A: attention ========
  {
    const int b  = xb[qrow];
    const int lo = seg[b];
    const int hi = seg[b + 1];

    const bf16x8 qf = *reinterpret_cast<const bf16x8*>(
        qb + (size_t)qrow * E + hd + g * 8);

    const int kstart = __shfl(lo, 0, 64);
    const int kend   = __shfl(hi, 15, 64);
    const int base   = kstart & ~63;

    const int base_l = ((l15 & 12) << 1) + (l15 & 3);  // 8*(l15>>2) + (l15&3)
    const int h4g    = h * 4 + g;                      // K chunk (16B) index

    f32x4 acc0 = {0.f, 0.f, 0.f, 0.f};
    f32x4 acc1 = {0.f, 0.f, 0.f, 0.f};
    float lsum = 0.f;

    // clean vmcnt slate so counted waits are exact
    asm volatile("s_waitcnt vmcnt(0)" ::: "memory");
    STAGE(ldsK0, ldsV0, base)

    int cur = 0;
    for (int j0 = base; j0 < kend; j0 += 64) {
      const bool pf = (j0 + 64) < kend;
      const __bf16* kc = cur ? ldsK1 : ldsK0;
      const __bf16* vc = cur ? ldsV1 : ldsV0;
      if (pf) {
        __bf16* kn = cur ? ldsK0 : ldsK1;
        __bf16* vn = cur ? ldsV0 : ldsV1;
        STAGE(kn, vn, j0 + 64)
        asm volatile("s_waitcnt vmcnt(8)" ::: "memory");
      } else {
        asm volatile("s_waitcnt vmcnt(0)" ::: "memory");
      }
      __builtin_amdgcn_s_barrier();
      __builtin_amdgcn_sched_barrier(0);

      // ---- QK^T from LDS (swizzled reads) ----
      f32x4 s[4];
#pragma unroll
      for (int mt = 0; mt < 4; ++mt) {
        const int r = base_l + 32 * (mt >> 1) + 4 * (mt & 1);
        const bf16x8 kf = *reinterpret_cast<const bf16x8*>(
            kc + r * 256 + ((h4g ^ (r & 7)) * 8));
        const f32x4 z = {0.f, 0.f, 0.f, 0.f};
        s[mt] = __builtin_amdgcn_mfma_f32_16x16x32_bf16(kf, qf, z, 0, 0, 0);
      }

      // ---- softmax numerators into P A-fragment slots ----
      bf16x8 pa[2];
#pragma unroll
      for (int ks = 0; ks < 2; ++ks)
#pragma unroll
        for (int b_ = 0; b_ < 2; ++b_)
#pragma unroll
          for (int r = 0; r < 4; ++r) {
            const int key = j0 + 32 * ks + 8 * g + 4 * b_ + r;
            const float sc = s[2 * ks + b_][r] * CL;
            const float e  = (key >= lo && key < hi) ? EXP2F(sc) : 0.f;
            lsum += e;
            pa[ks][4 * b_ + r] = (__bf16)e;
          }

      // ---- PV from LDS V (swizzled reads) ----
#pragma unroll
      for (int ks = 0; ks < 2; ++ks) {
        const int d0 = hd + l15;
        const int d1 = hd + 16 + l15;
        const bf16x8 vf0 = *reinterpret_cast<const bf16x8*>(
            vc + d0 * 64 + (((4 * ks + g) ^ (d0 & 7)) * 8));
        const bf16x8 vf1 = *reinterpret_cast<const bf16x8*>(
            vc + d1 * 64 + (((4 * ks + g) ^ (d1 & 7)) * 8));
        acc0 = __builtin_amdgcn_mfma_f32_16x16x32_bf16(pa[ks], vf0, acc0, 0, 0, 0);
        acc1 = __builtin_amdgcn_mfma_f32_16x16x32_bf16(pa[ks], vf1, acc1, 0, 0, 0);
      }

      __builtin_amdgcn_sched_barrier(0);
      __builtin_amdgcn_s_barrier();
      cur ^= 1;
    }

    lsum += __shfl_xor(lsum, 16, 64);
    lsum += __shfl_xor(lsum, 32, 64);
    const float inv = 1.0f / lsum;
    float invr[4];
#pragma unroll
    for (int r = 0; r < 4; ++r) invr[r] = __shfl(inv, 4 * g + r, 64);

#pragma unroll
    for (int r = 0; r < 4; ++r) {
      cl[4 * g + r][hd + l15]      = (__bf16)(acc0[r] * invr[r]);
      cl[4 * g + r][hd + 16 + l15] = (__bf16)(acc1[r] * invr[r]);
    }
  }
  __syncthreads();

  // ======== phase B: projection + residual + LayerNorm ========
  {
    bf16x8 af[8];
#pragma unroll
    for (int kk = 0; kk < 8; ++kk)
      af[kk] = *reinterpret_cast<const bf16x8*>(&cl[l15][kk * 32 + 8 * g]);

    f32x4 acc[2];
    acc[0] = f32x4{0.f, 0.f, 0.f, 0.f};
    acc[1] = f32x4{0.f, 0.f, 0.f, 0.f};

#pragma unroll
    for (int kk = 0; kk < 8; ++kk)
#pragma unroll
      for (int nt = 0; nt < 2; ++nt) {
        const bf16x8 wf = *reinterpret_cast<const bf16x8*>(
            wo + (size_t)(h * 32 + nt * 16 + l15) * E + kk * 32 + 8 * g);
        acc[nt] = __builtin_amdgcn_mfma_f32_16x16x32_bf16(af[kk], wf, acc[nt], 0, 0, 0);
      }

    float yv[2][4];
    float s1[4], s2[4];
#pragma unroll
    for (int r = 0; r < 4; ++r) { s1[r] = 0.f; s2[r] = 0.f; }
#pragma unroll
    for (int nt = 0; nt < 2; ++nt) {
      const int c = h * 32 + nt * 16 + l15;
      const float bb = bo[c];
#pragma unroll
      for (int r = 0; r < 4; ++r) {
        const int row = m0 + 4 * g + r;
        const float y = acc[nt][r] + bb + x[(size_t)row * E + c];
        yv[nt][r] = y;
        s1[r] += y;
        s2[r] += y * y;
      }
    }
#pragma unroll
    for (int off = 1; off < 16; off <<= 1) {
#pragma unroll
      for (int r = 0; r < 4; ++r) {
        s1[r] += __shfl_xor(s1[r], off, 64);
        s2[r] += __shfl_xor(s2[r], off, 64);
      }
    }
    if (l15 == 0) {
#pragma unroll
      for (int r = 0; r < 4; ++r) {
        redS[h][4 * g + r] = s1[r];
        redQ[h][4 * g + r] = s2[r];
      }
    }
    __syncthreads();
    float mu[4], rs[4];
#pragma unroll
    for (int r = 0; r < 4; ++r) {
      float ts = 0.f, tq = 0.f;
#pragma unroll
      for (int w = 0; w < 8; ++w) { ts += redS[w][4 * g + r]; tq += redQ[w][4 * g + r]; }
      mu[r] = ts * (1.0f / E);
      const float var = tq * (1.0f / E) - mu[r] * mu[r];
      rs[r] = rsqrtf(var + 1e-5f);
    }
#pragma unroll
    for (int nt = 0; nt < 2; ++nt) {
      const int c = h * 32 + nt * 16 + l15;
      const float gg = gamma[c];
      const float bt = beta[c];
#pragma unroll
      for (int r = 0; r < 4; ++r) {
        const int row = m0 + 4 * g + r;
        out[(size_t)row * E + c] = (yv[nt][r] - mu[r]) * rs[r] * gg + bt;
      }
    }
  }
}

}  // namespace

extern "C" void kernel_launch(void* const* d_in, const int* in_sizes, int n_in,
                              void* d_out, int out_size, void* d_ws, size_t ws_size,
                              hipStream_t stream) {
  const float* x     = (const float*)d_in[0];
  const float* pe    = (const float*)d_in[1];
  const int*   xb    = (const int*)d_in[2];
  const float* Wq    = (const float*)d_in[3];
  const float* Wk    = (const float*)d_in[4];
  const float* Wv    = (const float*)d_in[5];
  const float* bq    = (const float*)d_in[6];
  const float* bk    = (const float*)d_in[7];
  const float* bv    = (const float*)d_in[8];
  const float* Wo    = (const float*)d_in[9];
  const float* bo    = (const float*)d_in[10];
  const float* gamma = (const float*)d_in[11];
  const float* beta  = (const float*)d_in[12];
  float* out = (float*)d_out;

  char* wsb = (char*)d_ws;
  const size_t NE = (size_t)N * E;          // 1,048,576 elements
  __bf16* qb16  = (__bf16*)(wsb);                   // 2 MB
  __bf16* kb16  = (__bf16*)(wsb + 2 * NE);          // 2 MB
  __bf16* vt16  = (__bf16*)(wsb + 4 * NE);          // 2 MB  [E][N]
  __bf16* xpe16 = (__bf16*)(wsb + 6 * NE);          // 2 MB
  __bf16* xv16  = (__bf16*)(wsb + 8 * NE);          // 2 MB
  __bf16* wb16  = (__bf16*)(wsb + 10 * NE);         // 512 KB (4 mats)
  int*    seg   = (int*)(wsb + 10 * NE + 4 * (size_t)E * E * 2);

  prep_kernel<<<dim3(641), 256, 0, stream>>>(x, pe, xb, Wq, Wk, Wv, Wo,
                                             xpe16, xv16, wb16, seg);
  qkv_mfma<<<dim3(512, 3), 256, 0, stream>>>(xpe16, xv16, wb16, bq, bk, bv,
                                             qb16, kb16, vt16);
  attn_proj_ln<<<dim3(256), 512, 0, stream>>>(qb16, kb16, vt16, xb, seg,
                                              x, wb16 + 3 * (size_t)E * E,
                                              bo, gamma, beta, out);
}